// Round 8
// baseline (138.348 us; speedup 1.0000x reference)
//
#include <hip/hip_runtime.h>

// BPMLL loss, B=16384 rows, L=1024 cols, f32 in, scalar f32 out.
// Per row: pos = sum y*exp(-c); neg = sum (1-y)*exp(c);
// loss = pos*neg/(sum_y*(L-sum_y)); out = mean over rows.
//
// Ledger: R1/R2/R4 ~43us (3.1 TB/s). R6 (nt + persistent 512 blocks +
// register double-buffer) ~37us (3.6 TB/s). R7 doubled waves/CU -> neutral:
// in-flight parallelism is NOT the limiter. m146 proves single-stream reads
// hit 4.89 TB/s. Remaining variable: stream topology — we alternate c/y
// bursts every 4KB from bases 64MB apart. This round: 2-row pairs, 8KB
// contiguous c-burst then 8KB y-burst, double-buffered (R6 config otherwise).

#define NROWS 16384
#define NCOLS 1024
#define WPB 4
#define NBLOCKS 512                        // 2 blocks/CU, co-resident
#define ROWS_PER_WAVE (NROWS / (NBLOCKS * WPB))  // 8
#define PAIRS (ROWS_PER_WAVE / 2)          // 4 iterations of 2 rows

typedef float vf4 __attribute__((ext_vector_type(4)));
typedef int vi4 __attribute__((ext_vector_type(4)));

__device__ __forceinline__ void elem(float cv, int yv,
                                     float& pos, float& neg, float& cnt) {
    float t = __expf(yv ? -cv : cv);   // one transcendental per element
    pos += yv ? t : 0.f;
    neg += yv ? 0.f : t;
    cnt += (float)yv;
}

__device__ __forceinline__ void consume4(const vf4& cv, const vi4& yv,
                                         float& pos, float& neg, float& cnt) {
    elem(cv.x, yv.x, pos, neg, cnt);
    elem(cv.y, yv.y, pos, neg, cnt);
    elem(cv.z, yv.z, pos, neg, cnt);
    elem(cv.w, yv.w, pos, neg, cnt);
}

__device__ __forceinline__ float row_finish(float pos, float neg, float cnt) {
#pragma unroll
    for (int off = 1; off < 64; off <<= 1) {
        pos += __shfl_xor(pos, off);
        neg += __shfl_xor(neg, off);
        cnt += __shfl_xor(cnt, off);
    }
    return (pos * neg) / (cnt * ((float)NCOLS - cnt));  // BIAS=(1,1)
}

__global__ __launch_bounds__(256, 2) void bpmll_rows_kernel(
    const float* __restrict__ c, const int* __restrict__ y,
    float* __restrict__ partials) {
    const int wave = threadIdx.x >> 6;
    const int lane = threadIdx.x & 63;
    const int gw = blockIdx.x * WPB + wave;        // 0..2047
    const int row0 = gw * ROWS_PER_WAVE;           // 8 contiguous rows/wave

    const vf4* __restrict__ cp = (const vf4*)(c + (size_t)row0 * NCOLS);
    const vi4* __restrict__ yp = (const vi4*)(y + (size_t)row0 * NCOLS);
    // 2-row pair = 512 vf4/vi4 = 8KB contiguous per array

    vf4 cbuf[2][8];
    vi4 ybuf[2][8];

    // Prime: pair 0. Long same-array bursts (8 x dwordx4 nt back-to-back).
#pragma unroll
    for (int i = 0; i < 8; ++i)
        cbuf[0][i] = __builtin_nontemporal_load(&cp[lane + 64 * i]);
#pragma unroll
    for (int i = 0; i < 8; ++i)
        ybuf[0][i] = __builtin_nontemporal_load(&yp[lane + 64 * i]);

    float wave_loss = 0.f;
#pragma unroll
    for (int p = 0; p < PAIRS; ++p) {
        const int cur = p & 1, nxt = cur ^ 1;
        if (p < PAIRS - 1) {  // prefetch next pair while consuming this one
            const vf4* cn = cp + (size_t)(p + 1) * 512;
            const vi4* yn = yp + (size_t)(p + 1) * 512;
#pragma unroll
            for (int i = 0; i < 8; ++i)
                cbuf[nxt][i] = __builtin_nontemporal_load(&cn[lane + 64 * i]);
#pragma unroll
            for (int i = 0; i < 8; ++i)
                ybuf[nxt][i] = __builtin_nontemporal_load(&yn[lane + 64 * i]);
        }
        // Row A = bufs 0..3, row B = bufs 4..7 of the pair.
        float posA = 0.f, negA = 0.f, cntA = 0.f;
        float posB = 0.f, negB = 0.f, cntB = 0.f;
#pragma unroll
        for (int i = 0; i < 4; ++i) {
            consume4(cbuf[cur][i], ybuf[cur][i], posA, negA, cntA);
            consume4(cbuf[cur][i + 4], ybuf[cur][i + 4], posB, negB, cntB);
        }
        wave_loss += row_finish(posA, negA, cntA)
                   + row_finish(posB, negB, cntB);
    }

    __shared__ float acc[WPB];
    if (lane == 0) acc[wave] = wave_loss;
    __syncthreads();
    if (threadIdx.x == 0) {
        partials[blockIdx.x] =
            (acc[0] + acc[1] + acc[2] + acc[3]) * (1.0f / (float)NROWS);
    }
}

__global__ __launch_bounds__(256) void bpmll_reduce_kernel(
    const float* __restrict__ partials, float* __restrict__ out) {
    // 512 partials, 256 threads -> two floats per thread.
    float s = partials[threadIdx.x] + partials[threadIdx.x + 256];
#pragma unroll
    for (int off = 1; off < 64; off <<= 1) s += __shfl_xor(s, off);

    __shared__ float smem[4];
    const int lane = threadIdx.x & 63;
    const int wave = threadIdx.x >> 6;
    if (lane == 0) smem[wave] = s;
    __syncthreads();
    if (threadIdx.x == 0) out[0] = smem[0] + smem[1] + smem[2] + smem[3];
}

extern "C" void kernel_launch(void* const* d_in, const int* in_sizes, int n_in,
                              void* d_out, int out_size, void* d_ws, size_t ws_size,
                              hipStream_t stream) {
    const float* c = (const float*)d_in[0];
    const int* y = (const int*)d_in[1];
    float* partials = (float*)d_ws;   // NBLOCKS floats = 2 KiB scratch
    float* out = (float*)d_out;

    bpmll_rows_kernel<<<NBLOCKS, 256, 0, stream>>>(c, y, partials);
    bpmll_reduce_kernel<<<1, 256, 0, stream>>>(partials, out);
}